// Round 1
// baseline (78.869 us; speedup 1.0000x reference)
//
#include <hip/hip_runtime.h>

#define C_ 1000
#define D_ 512

typedef __bf16 bf16x4 __attribute__((ext_vector_type(4)));
typedef __bf16 bf16x8 __attribute__((ext_vector_type(8)));
typedef float  f32x4  __attribute__((ext_vector_type(4)));

__device__ __forceinline__ bf16x8 cvt8(float4 a, float4 b) {
    bf16x8 r;
    r[0] = (__bf16)a.x; r[1] = (__bf16)a.y; r[2] = (__bf16)a.z; r[3] = (__bf16)a.w;
    r[4] = (__bf16)b.x; r[5] = (__bf16)b.y; r[6] = (__bf16)b.z; r[7] = (__bf16)b.w;
    return r;
}
__device__ __forceinline__ bf16x4 cvt4(float4 a) {
    bf16x4 r;
    r[0] = (__bf16)a.x; r[1] = (__bf16)a.y; r[2] = (__bf16)a.z; r[3] = (__bf16)a.w;
    return r;
}

// Single fused kernel: no workspace, one launch.
// Block = (ct, bh): c-tile ct (4 classes = 16 W rows), b-half bh (128 x rows).
// bid swizzle pairs bh=0/1 of the same ct onto the same XCD (bids differ by 8)
// so the W tile is fetched from HBM once and L2-hit by the partner block.
// Per wave: 2 b-tiles; x MFMA fragments loaded directly into registers from
// fp32 x (L2-resident) and converted to bf16. x row norms come from the MFMA
// Gram trick (mfma(b,b) diagonal), same as the existing W-Gram path.
__global__ __launch_bounds__(256, 2) void k_fused(const float* __restrict__ x,
                                                  const float* __restrict__ W,
                                                  float* __restrict__ out) {
    __shared__ __align__(16) char smem[64 * 272];   // W frags: group g at g*272 + row*16 (17 KB)

    int bid = blockIdx.x;
    int ct = (bid & 7) + ((bid >> 4) << 3);   // pair (bid, bid+8) share ct, same XCD slot
    int bh = (bid >> 3) & 1;
    if (ct >= 250) return;                    // grid 512 covers ct 0..255; drop 250..255

    int t = threadIdx.x;
    int lane = t & 63, wv = t >> 6;
    int l15 = lane & 15, quad = lane >> 4;

    // ---- W tile (16 rows x 512 fp32) -> LDS bf16 fragments, coalesced ----
    const float* wbase = W + ct * (16 * D_);
    #pragma unroll
    for (int p = 0; p < 8; p++) {
        int ch = t + 256 * p;                 // 2048 float4 chunks
        int row = ch >> 7, pos = ch & 127;
        float4 v = *(const float4*)(wbase + row * D_ + pos * 4);
        int ks = pos >> 3, qd = (pos >> 1) & 3, off = (pos & 1) * 4;
        *(bf16x4*)(smem + (ks * 4 + qd) * 272 + row * 16 + off * 2) = cvt4(v);
    }

    // ---- x fragments straight into registers (2 b-tiles per wave) ----
    // frag(lt, ks) for lane (l15,quad) = x[(bt0+lt)*16 + l15][ks*32 + quad*8 .. +8]
    int bt0 = bh * 8 + wv * 2;
    bf16x8 bf[2][16];
    #pragma unroll
    for (int lt = 0; lt < 2; lt++) {
        const float* src = x + ((bt0 + lt) * 16 + l15) * D_ + quad * 8;
        #pragma unroll
        for (int ks = 0; ks < 16; ks++) {
            float4 va = *(const float4*)(src + ks * 32);
            float4 vb = *(const float4*)(src + ks * 32 + 4);
            bf[lt][ks] = cvt8(va, vb);
        }
    }
    __syncthreads();

    const char* lp = smem + quad * 272 + l15 * 16;
    f32x4 acc0  = {0.f, 0.f, 0.f, 0.f};   // W-tile x x-tile0 logits
    f32x4 acc1  = {0.f, 0.f, 0.f, 0.f};   // W-tile x x-tile1 logits
    f32x4 accg  = {0.f, 0.f, 0.f, 0.f};   // W Gram (for iv)
    f32x4 accx0 = {0.f, 0.f, 0.f, 0.f};   // x Gram tile0 (diag = row sumsq)
    f32x4 accx1 = {0.f, 0.f, 0.f, 0.f};   // x Gram tile1
    #pragma unroll
    for (int ks = 0; ks < 16; ks++) {
        bf16x8 af = *(const bf16x8*)(lp + ks * 1088);
        bf16x8 b0 = bf[0][ks];
        bf16x8 b1 = bf[1][ks];
        acc0  = __builtin_amdgcn_mfma_f32_16x16x32_bf16(af, b0, acc0, 0, 0, 0);
        acc1  = __builtin_amdgcn_mfma_f32_16x16x32_bf16(af, b1, acc1, 0, 0, 0);
        accg  = __builtin_amdgcn_mfma_f32_16x16x32_bf16(af, af, accg, 0, 0, 0);
        accx0 = __builtin_amdgcn_mfma_f32_16x16x32_bf16(b0, b0, accx0, 0, 0, 0);
        accx1 = __builtin_amdgcn_mfma_f32_16x16x32_bf16(b1, b1, accx1, 0, 0, 0);
    }

    // lane's 4x4 W-Gram block: Gram[4q+s][4q+qq] lives in lane 20*quad+qq, reg s
    float g[4][4];
    #pragma unroll
    for (int s = 0; s < 4; s++) {
        float v = accg[s];
        #pragma unroll
        for (int q = 0; q < 4; q++) g[s][q] = __shfl(v, 20 * quad + q);
    }
    float iv[4];
    #pragma unroll
    for (int s = 0; s < 4; s++) iv[s] = 1.0f / fmaxf(sqrtf(fmaxf(g[s][s], 0.f)), 1e-12f);

    // x-Gram diag extraction: diag[l15] lives in lane (l15>>2)*16 + l15, reg l15&3
    int sd = l15 & 3;
    int srcl = ((l15 >> 2) << 4) + l15;

    #pragma unroll
    for (int sub = 0; sub < 2; sub++) {
        int bt = bt0 + sub;
        f32x4 acc = sub ? acc1 : acc0;
        f32x4 ax  = sub ? accx1 : accx0;
        float cand = (sd == 0) ? ax[0] : (sd == 1) ? ax[1] : (sd == 2) ? ax[2] : ax[3];
        float dg = __shfl(cand, srcl);
        float ivx = 1.0f / fmaxf(sqrtf(fmaxf(dg, 0.f)), 1e-12f);

        float l[4];
        #pragma unroll
        for (int s = 0; s < 4; s++) l[s] = acc[s] * ivx * iv[s];
        float num = l[0]*l[0] + l[1]*l[1] + l[2]*l[2] + l[3]*l[3];
        float den2 = 0.f;
        #pragma unroll
        for (int s = 0; s < 4; s++) {
            float r = 0.f;
            #pragma unroll
            for (int q = 0; q < 4; q++) r += g[s][q] * iv[q] * l[q];
            den2 += l[s] * iv[s] * r;
        }
        float den = fmaxf(sqrtf(fmaxf(den2, 0.f)), 1e-12f);
        float val = num / den;

        float4 o;   // pack c = ct*4..ct*4+3 for row b into one 16B store
        o.x = __shfl(val, l15);
        o.y = __shfl(val, l15 + 16);
        o.z = __shfl(val, l15 + 32);
        o.w = __shfl(val, l15 + 48);
        if (quad == 0)
            *(float4*)(out + (bt * 16 + l15) * C_ + ct * 4) = o;
    }
}

extern "C" void kernel_launch(void* const* d_in, const int* in_sizes, int n_in,
                              void* d_out, int out_size, void* d_ws, size_t ws_size,
                              hipStream_t stream) {
    const float* x = (const float*)d_in[0];   // [256,512] fp32
    const float* W = (const float*)d_in[1];   // [1000,4,512] fp32
    float* out = (float*)d_out;               // [256,1000] fp32

    (void)d_ws; (void)ws_size;                // workspace no longer used
    k_fused<<<512, 256, 0, stream>>>(x, W, out);
}

// Round 2
// 67.611 us; speedup vs baseline: 1.1665x; 1.1665x over previous
//
#include <hip/hip_runtime.h>

#define B_ 256
#define C_ 1000
#define D_ 512

typedef __bf16 bf16x4 __attribute__((ext_vector_type(4)));
typedef __bf16 bf16x8 __attribute__((ext_vector_type(8)));
typedef float  f32x4  __attribute__((ext_vector_type(4)));

__device__ __forceinline__ bf16x8 cvt8(float4 a, float4 b) {
    bf16x8 r;
    r[0] = (__bf16)a.x; r[1] = (__bf16)a.y; r[2] = (__bf16)a.z; r[3] = (__bf16)a.w;
    r[4] = (__bf16)b.x; r[5] = (__bf16)b.y; r[6] = (__bf16)b.z; r[7] = (__bf16)b.w;
    return r;
}
__device__ __forceinline__ bf16x4 cvt4(float4 a) {
    bf16x4 r;
    r[0] = (__bf16)a.x; r[1] = (__bf16)a.y; r[2] = (__bf16)a.z; r[3] = (__bf16)a.w;
    return r;
}

// Pack x (512 KB) to bf16 MFMA-fragment layout [bt][ks][quad][l15][8] + invx[b].
// 64 blocks; one wave == one x row; coalesced fp32 reads; tiny scattered writes.
__global__ __launch_bounds__(256) void k_packx(const float* __restrict__ x,
                                               __bf16* __restrict__ xf,
                                               float* __restrict__ invx) {
    int n = blockIdx.x * 256 + threadIdx.x;   // 16384 chunks of 8 elems
    int r = n >> 6;                           // x row 0..255 (wave-uniform)
    int j = n & 63;                           // chunk in row
    const float* src = x + r * D_ + j * 8;
    float4 a = *(const float4*)src;
    float4 b = *(const float4*)(src + 4);
    int bt = r >> 4, l15 = r & 15, ks = j >> 2, quad = j & 3;
    int idx = ((bt * 16 + ks) * 4 + quad) * 16 + l15;
    *(bf16x8*)(xf + idx * 8) = cvt8(a, b);
    float sn = a.x*a.x + a.y*a.y + a.z*a.z + a.w*a.w
             + b.x*b.x + b.y*b.y + b.z*b.z + b.w*b.w;
    #pragma unroll
    for (int o = 32; o; o >>= 1) sn += __shfl_down(sn, o);
    if ((threadIdx.x & 63) == 0) invx[r] = 1.0f / fmaxf(sqrtf(sn), 1e-12f);
}

// Main v2: 1 b-tile per wave (was 2), grid 1024 (4 blocks per c-tile; bids
// differing by 8 share the XCD so the W tile is HBM-fetched once, L2-hit 3x).
// All 16 xf B-fragments are hoisted into registers BEFORE the W prologue so
// their L2 latency overlaps the W HBM load + LDS staging.
__global__ __launch_bounds__(256, 3) void k_main(const float* __restrict__ W,
                                                 const __bf16* __restrict__ xf,
                                                 const float* __restrict__ invx,
                                                 float* __restrict__ out) {
    __shared__ __align__(16) char smem[64 * 272];   // W frags: group g at g*272 + row*16
    int bid = blockIdx.x;
    int ct = (bid & 7) + ((bid >> 5) << 3);   // blocks {k, k+8, k+16, k+24} share ct & XCD slot
    int bq = (bid >> 3) & 3;                  // b quarter
    if (ct >= 250) return;

    int t = threadIdx.x;
    int lane = t & 63, wv = t >> 6;
    int l15 = lane & 15, quad = lane >> 4;

    int bt = bq * 4 + wv;                     // this wave's single b-tile (0..15)

    // ---- hoisted x fragments (L2-resident; overlap with W prologue) ----
    const bf16x8* xp = (const bf16x8*)xf + (bt * 64 + quad) * 16 + l15;
    bf16x8 bfr[16];
    #pragma unroll
    for (int ks = 0; ks < 16; ks++) bfr[ks] = xp[ks * 64];

    // ---- W tile (16 rows x 512 fp32) -> LDS bf16 fragments, coalesced ----
    const float* wbase = W + ct * (16 * D_);
    #pragma unroll
    for (int p = 0; p < 8; p++) {
        int ch = t + 256 * p;                 // 2048 float4 chunks
        int row = ch >> 7, pos = ch & 127;
        float4 v = *(const float4*)(wbase + row * D_ + pos * 4);
        int ks = pos >> 3, qd = (pos >> 1) & 3, off = (pos & 1) * 4;
        *(bf16x4*)(smem + (ks * 4 + qd) * 272 + row * 16 + off * 2) = cvt4(v);
    }
    __syncthreads();

    const char* lp = smem + quad * 272 + l15 * 16;
    f32x4 acc  = {0.f, 0.f, 0.f, 0.f};
    f32x4 accg = {0.f, 0.f, 0.f, 0.f};
    #pragma unroll
    for (int ks = 0; ks < 16; ks++) {
        bf16x8 af = *(const bf16x8*)(lp + ks * 1088);
        acc  = __builtin_amdgcn_mfma_f32_16x16x32_bf16(af, bfr[ks], acc, 0, 0, 0);
        accg = __builtin_amdgcn_mfma_f32_16x16x32_bf16(af, af, accg, 0, 0, 0);
    }

    // lane's 4x4 Gram block: Gram[4q+s][4q+qq] is in lane 20*quad+qq, reg s
    float g[4][4];
    #pragma unroll
    for (int s = 0; s < 4; s++) {
        float v = accg[s];
        #pragma unroll
        for (int q = 0; q < 4; q++) g[s][q] = __shfl(v, 20 * quad + q);
    }
    float iv[4];
    #pragma unroll
    for (int s = 0; s < 4; s++) iv[s] = 1.0f / fmaxf(sqrtf(fmaxf(g[s][s], 0.f)), 1e-12f);

    float ivx = invx[bt * 16 + l15];
    float l[4];
    #pragma unroll
    for (int s = 0; s < 4; s++) l[s] = acc[s] * ivx * iv[s];
    float num = l[0]*l[0] + l[1]*l[1] + l[2]*l[2] + l[3]*l[3];
    float den2 = 0.f;
    #pragma unroll
    for (int s = 0; s < 4; s++) {
        float r = 0.f;
        #pragma unroll
        for (int q = 0; q < 4; q++) r += g[s][q] * iv[q] * l[q];
        den2 += l[s] * iv[s] * r;
    }
    float den = fmaxf(sqrtf(fmaxf(den2, 0.f)), 1e-12f);
    float val = num / den;

    float4 o;   // pack c = ct*4..ct*4+3 for row b into one 16B store
    o.x = __shfl(val, l15);
    o.y = __shfl(val, l15 + 16);
    o.z = __shfl(val, l15 + 32);
    o.w = __shfl(val, l15 + 48);
    if (quad == 0)
        *(float4*)(out + (bt * 16 + l15) * C_ + ct * 4) = o;
}

extern "C" void kernel_launch(void* const* d_in, const int* in_sizes, int n_in,
                              void* d_out, int out_size, void* d_ws, size_t ws_size,
                              hipStream_t stream) {
    const float* x = (const float*)d_in[0];   // [256,512] fp32
    const float* W = (const float*)d_in[1];   // [1000,4,512] fp32
    float* out = (float*)d_out;               // [256,1000] fp32

    char* ws = (char*)d_ws;
    __bf16* xf  = (__bf16*)ws;                // 256*512*2 = 524,288 B
    float*  ivx = (float*)(ws + 524288);      // 1024 B

    k_packx<<<64, 256, 0, stream>>>(x, xf, ivx);
    k_main<<<1024, 256, 0, stream>>>(W, xf, ivx, out);
}